// Round 1
// baseline (47.220 us; speedup 1.0000x reference)
//
#include <hip/hip_runtime.h>
#include <math.h>

// YOLO box decode: x[B=32, A*(NC+5)=255, G=52, G=52] f32 ->
// out[B, A*G*G=8112, 85] f32  (+ trailing scalar 0 from the tuple return).
//
// out[b, a*G*G + cell, k]:
//   k==0: (sigmoid(x0)+gx)*stride, k==1: (sigmoid(x1)+gy)*stride
//   k==2: exp(x2)*ANCH[a][0],      k==3: exp(x3)*ANCH[a][1]
//   k>=4: sigmoid(xk)
// stride = 416/52 = 8.0 (exact pow2; anchor/8*8 is exact).

#define NB    32
#define NA    3
#define NCH   85
#define GG    52
#define CELLS (GG * GG)          // 2704
#define TILE  128                // cells per block
#define NTILES ((CELLS + TILE - 1) / TILE)   // 22 (21 full + tail of 16)
#define STRIDEF 8.0f

__device__ __forceinline__ float sigm(float v) {
    return 1.0f / (1.0f + expf(-v));
}

__global__ __launch_bounds__(256) void yolo_decode(const float* __restrict__ x,
                                                   float* __restrict__ out) {
    __shared__ __align__(16) float lds[TILE * NCH];   // 43.5 KB -> ~3 blocks/CU

    const int tile = blockIdx.x;
    const int a    = blockIdx.y;
    const int b    = blockIdx.z;
    const int cell0 = tile * TILE;
    const int ncell = min(TILE, CELLS - cell0);       // 128 or 16

    const int lane = threadIdx.x & 63;
    const int wv   = threadIdx.x >> 6;                // 0..3

    const float aw = (a == 0) ? 10.0f : (a == 1) ? 16.0f : 33.0f;
    const float ah = (a == 0) ? 13.0f : (a == 1) ? 30.0f : 23.0f;

    // input base for this (b, a), at cell0
    const float* xb = x + ((size_t)(b * NA + a) * NCH) * CELLS + cell0;

    const int c2 = lane * 2;                          // local cell pair
    if (c2 < ncell) {
        const int cellA = cell0 + c2;
        const int cellB = cellA + 1;
        const float gxA = (float)(cellA % GG), gyA = (float)(cellA / GG);
        const float gxB = (float)(cellB % GG), gyB = (float)(cellB / GG);

        for (int ch = wv; ch < NCH; ch += 4) {
            // coalesced: wave reads 64 lanes x 8B = 512B contiguous
            const float2 v = *(const float2*)(xb + (size_t)ch * CELLS + c2);
            float r0, r1;
            if (ch == 0) {
                r0 = (sigm(v.x) + gxA) * STRIDEF;
                r1 = (sigm(v.y) + gxB) * STRIDEF;
            } else if (ch == 1) {
                r0 = (sigm(v.x) + gyA) * STRIDEF;
                r1 = (sigm(v.y) + gyB) * STRIDEF;
            } else if (ch == 2) {
                r0 = expf(v.x) * aw;
                r1 = expf(v.y) * aw;
            } else if (ch == 3) {
                r0 = expf(v.x) * ah;
                r1 = expf(v.y) * ah;
            } else {
                r0 = sigm(v.x);
                r1 = sigm(v.y);
            }
            // LDS in output order: lds[localCell*85 + ch]
            lds[c2 * NCH + ch]       = r0;
            lds[(c2 + 1) * NCH + ch] = r1;
        }
    }
    __syncthreads();

    // coalesced float4 writeback: ncell*85 floats are contiguous in out,
    // base and count are 16B-aligned (128*85 and 16*85 both divisible by 4).
    float* ob = out + ((size_t)((b * NA + a) * CELLS + cell0)) * NCH;
    const int total4 = (ncell * NCH) >> 2;            // 2720 or 340
    const float4* l4 = (const float4*)lds;
    float4* o4 = (float4*)ob;
    for (int j = threadIdx.x; j < total4; j += 256) {
        o4[j] = l4[j];
    }
}

__global__ void zero_tail(float* __restrict__ out, long long start, long long n) {
    long long i = (long long)blockIdx.x * blockDim.x + threadIdx.x;
    if (i < n) out[start + i] = 0.0f;
}

extern "C" void kernel_launch(void* const* d_in, const int* in_sizes, int n_in,
                              void* d_out, int out_size, void* d_ws, size_t ws_size,
                              hipStream_t stream) {
    const float* x = (const float*)d_in[0];
    float* out = (float*)d_out;

    dim3 grid(NTILES, NA, NB);      // 22 x 3 x 32 = 2112 blocks
    yolo_decode<<<grid, 256, 0, stream>>>(x, out);

    const long long MAIN = (long long)NB * NA * CELLS * NCH;  // 22,064,640
    if ((long long)out_size > MAIN) {
        long long n = (long long)out_size - MAIN;             // the tuple's scalar 0
        int blocks = (int)((n + 255) / 256);
        zero_tail<<<blocks, 256, 0, stream>>>(out, MAIN, n);
    }
}

// Round 2
// 37.553 us; speedup vs baseline: 1.2574x; 1.2574x over previous
//
#include <hip/hip_runtime.h>
#include <math.h>

// YOLO box decode: x[B=32, A*(NC+5)=255, G=52, G=52] f32 ->
// out[B, A*G*G=8112, 85] f32  (+ trailing scalar 0 from the tuple return).
//
// out[b, a*G*G + cell, k]:
//   k==0: (sigmoid(x0)+gx)*stride, k==1: (sigmoid(x1)+gy)*stride
//   k==2: exp(x2)*ANCH[a][0],      k==3: exp(x3)*ANCH[a][1]
//   k>=4: sigmoid(xk)
// stride = 416/52 = 8.0 (exact pow2; anchor/8*8 is exact).
//
// R1: TILE 128->64 (LDS 43.5KB->21.76KB => 7 blocks/CU, ~87% occupancy cap;
//     R0 measured Occupancy=27% latency-bound). float4 reads (1KB/wave/instr).
//     __expf/__fdividef native transcendentals (VALU headroom at 3x occupancy).

#define NB    32
#define NA    3
#define NCH   85
#define GG    52
#define CELLS (GG * GG)          // 2704
#define TILE  64                 // cells per block
#define NTILES ((CELLS + TILE - 1) / TILE)   // 43 (42 full + tail of 16)
#define STRIDEF 8.0f

__device__ __forceinline__ float sigm(float v) {
    return __fdividef(1.0f, 1.0f + __expf(-v));
}

__global__ __launch_bounds__(256, 7) void yolo_decode(const float* __restrict__ x,
                                                      float* __restrict__ out) {
    __shared__ __align__(16) float lds[TILE * NCH];   // 21.76 KB -> 7 blocks/CU

    const int tile = blockIdx.x;
    const int a    = blockIdx.y;
    const int b    = blockIdx.z;
    const int cell0 = tile * TILE;
    const int ncell = min(TILE, CELLS - cell0);       // 64 or 16

    const int lane = threadIdx.x & 63;
    const int wv   = threadIdx.x >> 6;                // 0..3

    const float aw = (a == 0) ? 10.0f : (a == 1) ? 16.0f : 33.0f;
    const float ah = (a == 0) ? 13.0f : (a == 1) ? 30.0f : 23.0f;

    // input base for this (b, a), at cell0
    const float* xb = x + ((size_t)(b * NA + a) * NCH) * CELLS + cell0;

    const int grp = lane >> 4;                        // 0..3: channel sub-group
    const int c4  = (lane & 15) * 4;                  // local cell (x4)
    if (c4 < ncell) {
        // grid coords for the 4 cells this lane owns
        float gx[4], gy[4];
        #pragma unroll
        for (int j = 0; j < 4; ++j) {
            const int cell = cell0 + c4 + j;
            gx[j] = (float)(cell % GG);
            gy[j] = (float)(cell / GG);
        }

        // wave covers 4 consecutive channels per iter: 16 lanes x 16B = 256B
        // per channel, 1KB per wave instruction. 85 channels in 6 iters.
        for (int ch = wv * 4 + grp; ch < NCH; ch += 16) {
            const float4 v = *(const float4*)(xb + (size_t)ch * CELLS + c4);
            float r[4] = {v.x, v.y, v.z, v.w};
            if (ch == 0) {
                #pragma unroll
                for (int j = 0; j < 4; ++j) r[j] = (sigm(r[j]) + gx[j]) * STRIDEF;
            } else if (ch == 1) {
                #pragma unroll
                for (int j = 0; j < 4; ++j) r[j] = (sigm(r[j]) + gy[j]) * STRIDEF;
            } else if (ch == 2) {
                #pragma unroll
                for (int j = 0; j < 4; ++j) r[j] = __expf(r[j]) * aw;
            } else if (ch == 3) {
                #pragma unroll
                for (int j = 0; j < 4; ++j) r[j] = __expf(r[j]) * ah;
            } else {
                #pragma unroll
                for (int j = 0; j < 4; ++j) r[j] = sigm(r[j]);
            }
            // LDS in output order: lds[localCell*85 + ch]
            #pragma unroll
            for (int j = 0; j < 4; ++j) lds[(c4 + j) * NCH + ch] = r[j];
        }
    }
    __syncthreads();

    // coalesced float4 writeback: ncell*85 floats are contiguous in out,
    // base and count are 16B-aligned (64*85 and 16*85 both divisible by 4).
    float* ob = out + ((size_t)((b * NA + a) * CELLS + cell0)) * NCH;
    const int total4 = (ncell * NCH) >> 2;            // 1360 or 340
    const float4* l4 = (const float4*)lds;
    float4* o4 = (float4*)ob;
    for (int j = threadIdx.x; j < total4; j += 256) {
        o4[j] = l4[j];
    }
}

__global__ void zero_tail(float* __restrict__ out, long long start, long long n) {
    long long i = (long long)blockIdx.x * blockDim.x + threadIdx.x;
    if (i < n) out[start + i] = 0.0f;
}

extern "C" void kernel_launch(void* const* d_in, const int* in_sizes, int n_in,
                              void* d_out, int out_size, void* d_ws, size_t ws_size,
                              hipStream_t stream) {
    const float* x = (const float*)d_in[0];
    float* out = (float*)d_out;

    dim3 grid(NTILES, NA, NB);      // 43 x 3 x 32 = 4128 blocks
    yolo_decode<<<grid, 256, 0, stream>>>(x, out);

    const long long MAIN = (long long)NB * NA * CELLS * NCH;  // 22,064,640
    if ((long long)out_size > MAIN) {
        long long n = (long long)out_size - MAIN;             // the tuple's scalar 0
        int blocks = (int)((n + 255) / 256);
        zero_tail<<<blocks, 256, 0, stream>>>(out, MAIN, n);
    }
}

// Round 4
// 35.727 us; speedup vs baseline: 1.3217x; 1.0511x over previous
//
#include <hip/hip_runtime.h>
#include <math.h>

// YOLO box decode: x[B=32, A*(NC+5)=255, G=52, G=52] f32 ->
// out[B, A*G*G=8112, 85] f32  (+ trailing scalar 0 from the tuple return).
//
// R1: TILE 64 (21.76KB LDS -> 7 blocks/CU), float4 reads, native exp.
// R2 post-mortem: latency-bound (Occ 55%, VALU 23%, HBM 34%). MLP~1 per wave
//     (runtime-trip loops serialize load->use). R3: fully unrolled phases --
//     6 global loads in flight, then 6 ds_read_b128 in flight; nontemporal
//     output stores (keep 88MB input resident in L3: FETCH was 54MB<88MB);
//     zero-tail folded into main kernel.
// R4: fix compile -- __builtin_nontemporal_store needs a plain vector type,
//     not HIP_vector_type float4; use ext_vector_type(4) float.

#define NB    32
#define NA    3
#define NCH   85
#define GG    52
#define CELLS (GG * GG)          // 2704
#define TILE  64                 // cells per block
#define NTILES ((CELLS + TILE - 1) / TILE)   // 43 (42 full + tail of 16)
#define STRIDEF 8.0f

typedef float f32x4 __attribute__((ext_vector_type(4)));

__device__ __forceinline__ float sigm(float v) {
    return __fdividef(1.0f, 1.0f + __expf(-v));
}

__global__ __launch_bounds__(256, 7) void yolo_decode(const float* __restrict__ x,
                                                      float* __restrict__ out,
                                                      long long out_size) {
    __shared__ __align__(16) float lds[TILE * NCH];   // 21.76 KB -> 7 blocks/CU

    const int tile = blockIdx.x;
    const int a    = blockIdx.y;
    const int b    = blockIdx.z;
    const int cell0 = tile * TILE;
    const int ncell = min(TILE, CELLS - cell0);       // 64 or 16

    const int lane = threadIdx.x & 63;
    const int wv   = threadIdx.x >> 6;                // 0..3

    const float aw = (a == 0) ? 10.0f : (a == 1) ? 16.0f : 33.0f;
    const float ah = (a == 0) ? 13.0f : (a == 1) ? 30.0f : 23.0f;

    // fold the tuple's trailing scalar 0 into this kernel (no extra launch)
    const long long MAIN = (long long)NB * NA * CELLS * NCH;
    if (tile == 0 && a == 0 && b == 0 && threadIdx.x == 0 && out_size > MAIN) {
        for (long long i = MAIN; i < out_size; ++i) out[i] = 0.0f;
    }

    // input base for this (b, a), at cell0
    const float* xb = x + ((size_t)(b * NA + a) * NCH) * CELLS + cell0;

    const int grp   = lane >> 4;                      // 0..3: channel sub-group
    const int c4    = (lane & 15) * 4;                // local cell (x4)
    const int start = wv * 4 + grp;                   // first channel: 0..15

    if (c4 < ncell) {
        float gx[4], gy[4];
        #pragma unroll
        for (int j = 0; j < 4; ++j) {
            const int cell = cell0 + c4 + j;
            gx[j] = (float)(cell % GG);
            gy[j] = (float)(cell / GG);
        }

        // channels: start + 16k. k=0..4 always valid (start<=15 -> ch<=79);
        // k=5 valid iff start<5 (ch=start+80<85).
        // Issue ALL loads first -> 5-6 outstanding global loads per thread.
        f32x4 v[6];
        #pragma unroll
        for (int k = 0; k < 5; ++k)
            v[k] = *(const f32x4*)(xb + (size_t)(start + 16 * k) * CELLS + c4);
        const bool has6 = (start < 5);
        if (has6)
            v[5] = *(const f32x4*)(xb + (size_t)(start + 80) * CELLS + c4);

        // transform: only k==0 can hit the 4 special channels (ch=start<16)
        {
            float r[4] = {v[0].x, v[0].y, v[0].z, v[0].w};
            if (start == 0) {
                #pragma unroll
                for (int j = 0; j < 4; ++j) r[j] = (sigm(r[j]) + gx[j]) * STRIDEF;
            } else if (start == 1) {
                #pragma unroll
                for (int j = 0; j < 4; ++j) r[j] = (sigm(r[j]) + gy[j]) * STRIDEF;
            } else if (start == 2) {
                #pragma unroll
                for (int j = 0; j < 4; ++j) r[j] = __expf(r[j]) * aw;
            } else if (start == 3) {
                #pragma unroll
                for (int j = 0; j < 4; ++j) r[j] = __expf(r[j]) * ah;
            } else {
                #pragma unroll
                for (int j = 0; j < 4; ++j) r[j] = sigm(r[j]);
            }
            #pragma unroll
            for (int j = 0; j < 4; ++j) lds[(c4 + j) * NCH + start] = r[j];
        }
        #pragma unroll
        for (int k = 1; k < 5; ++k) {
            const int ch = start + 16 * k;
            float r[4] = {v[k].x, v[k].y, v[k].z, v[k].w};
            #pragma unroll
            for (int j = 0; j < 4; ++j) lds[(c4 + j) * NCH + ch] = sigm(r[j]);
        }
        if (has6) {
            const int ch = start + 80;
            float r[4] = {v[5].x, v[5].y, v[5].z, v[5].w};
            #pragma unroll
            for (int j = 0; j < 4; ++j) lds[(c4 + j) * NCH + ch] = sigm(r[j]);
        }
    }
    __syncthreads();

    // coalesced float4 writeback, fully unrolled: issue all ds_reads, then
    // all nontemporal global stores. total4 = 1360 (full) or 340 (tail).
    float* ob = out + ((size_t)((b * NA + a) * CELLS + cell0)) * NCH;
    const int total4 = (ncell * NCH) >> 2;
    const f32x4* l4 = (const f32x4*)lds;
    f32x4* o4 = (f32x4*)ob;

    f32x4 t[6];
    #pragma unroll
    for (int k = 0; k < 6; ++k) {
        const int j = (int)threadIdx.x + 256 * k;
        if (j < total4) t[k] = l4[j];
    }
    #pragma unroll
    for (int k = 0; k < 6; ++k) {
        const int j = (int)threadIdx.x + 256 * k;
        if (j < total4) __builtin_nontemporal_store(t[k], &o4[j]);
    }
}

extern "C" void kernel_launch(void* const* d_in, const int* in_sizes, int n_in,
                              void* d_out, int out_size, void* d_ws, size_t ws_size,
                              hipStream_t stream) {
    const float* x = (const float*)d_in[0];
    float* out = (float*)d_out;

    dim3 grid(NTILES, NA, NB);      // 43 x 3 x 32 = 4128 blocks
    yolo_decode<<<grid, 256, 0, stream>>>(x, out, (long long)out_size);
}